// Round 1
// baseline (4793.024 us; speedup 1.0000x reference)
//
#include <hip/hip_runtime.h>
#include <math.h>

// ---------------- constants (match reference) ----------------
#define N_NODES 4096
#define D_IN    768
#define H1      384
#define H2      256
#define H3      512
#define D_OUT   128
#define E_EDGES 8192
#define K_MID   129
#define ALPHA   0.2f
#define NEGV    -9000000000000000.0f

// ---------------- helpers ----------------
__device__ __forceinline__ float eluf(float x) {
    return x > 0.f ? x : expm1f(x);
}

template<int ACT>  // 0 = leaky_relu(0.2), 1 = elu
__device__ __forceinline__ float actf(float x) {
    if (ACT == 0) return x >= 0.f ? x : ALPHA * x;
    else          return x > 0.f ? x : expm1f(x);
}

__device__ __forceinline__ float waveReduceMax(float v) {
    #pragma unroll
    for (int off = 32; off; off >>= 1) v = fmaxf(v, __shfl_xor(v, off));
    return v;
}
__device__ __forceinline__ float waveReduceSum(float v) {
    #pragma unroll
    for (int off = 32; off; off >>= 1) v += __shfl_xor(v, off);
    return v;
}

// ---------------- generic fp32 GEMM: C = act(A@B + bias) ----------------
// Tile 64x128, 256 threads, 4x8 per thread, BK=16.
// Requires M%64==0, N%128==0, K%16==0 (true for all call sites).
template<int ACT>  // 0: none, 1: elu(v + bias[c])
__global__ __launch_bounds__(256)
void gemm_f32(const float* __restrict__ A, const float* __restrict__ B,
              const float* __restrict__ bias, float* __restrict__ C,
              int M, int K, int Nc)
{
    __shared__ float As[16][68];    // [k][i], padded
    __shared__ float Bs[16][132];   // [k][c], padded
    const int t  = threadIdx.x;
    const int i0 = blockIdx.x * 64;
    const int c0 = blockIdx.y * 128;
    const int rg = t >> 4;          // 0..15 -> rows rg*4..+3
    const int cg = t & 15;          // 0..15 -> cols cg*8..+7
    float acc[4][8] = {};

    for (int k0 = 0; k0 < K; k0 += 16) {
        {   // A tile 64x16 (float4 over k, transpose into [k][i])
            int i = t & 63, kq = t >> 6;
            float4 v = *(const float4*)(A + (size_t)(i0 + i) * K + k0 + (kq << 2));
            As[(kq << 2) + 0][i] = v.x;
            As[(kq << 2) + 1][i] = v.y;
            As[(kq << 2) + 2][i] = v.z;
            As[(kq << 2) + 3][i] = v.w;
        }
        {   // B tile 16x128
            int kb = t >> 5, cc4 = (t & 31) << 2;
            #pragma unroll
            for (int p = 0; p < 2; ++p) {
                int k = kb + (p << 3);
                float4 v = *(const float4*)(B + (size_t)(k0 + k) * Nc + c0 + cc4);
                *(float4*)&Bs[k][cc4] = v;
            }
        }
        __syncthreads();
        #pragma unroll
        for (int k = 0; k < 16; ++k) {
            float4 a4 = *(const float4*)&As[k][rg << 2];
            float4 b0 = *(const float4*)&Bs[k][cg << 3];
            float4 b1 = *(const float4*)&Bs[k][(cg << 3) + 4];
            float wa[4] = {a4.x, a4.y, a4.z, a4.w};
            float hb[8] = {b0.x, b0.y, b0.z, b0.w, b1.x, b1.y, b1.z, b1.w};
            #pragma unroll
            for (int a = 0; a < 4; ++a)
                #pragma unroll
                for (int b = 0; b < 8; ++b)
                    acc[a][b] += wa[a] * hb[b];
        }
        __syncthreads();
    }
    #pragma unroll
    for (int a = 0; a < 4; ++a) {
        int row = i0 + (rg << 2) + a;
        float* op = C + (size_t)row * Nc + c0 + (cg << 3);
        #pragma unroll
        for (int b = 0; b < 8; ++b) {
            float v = acc[a][b];
            if (ACT == 1) v = eluf(v + bias[c0 + (cg << 3) + b]);
            op[b] = v;
        }
    }
}

// ---------------- s1/s2 row dots: s1[i]=h[i,:]@a[0:K], s2[i]=h[i,:]@a[K:2K] ----------------
__global__ __launch_bounds__(64)
void rowdot2(const float* __restrict__ h, const float* __restrict__ a, int K,
             float* __restrict__ s1, float* __restrict__ s2)
{
    const int i = blockIdx.x, lane = threadIdx.x;
    const float* hp = h + (size_t)i * K;
    float p1 = 0.f, p2 = 0.f;
    for (int k = lane; k < K; k += 64) {
        float hv = hp[k];
        p1 += hv * a[k];
        p2 += hv * a[K + k];
    }
    p1 = waveReduceSum(p1);
    p2 = waveReduceSum(p2);
    if (lane == 0) { s1[i] = p1; s2[i] = p2; }
}

// ---------------- per-row softmax stats: mrow[i]=max_j l_ij, rrow[i]=1/sum_j exp(l-m) ----------------
template<int ACT>
__global__ __launch_bounds__(256)
void softmax_stats(const float* __restrict__ s1, const float* __restrict__ s2,
                   const int* __restrict__ adj, float* __restrict__ mrow,
                   float* __restrict__ rrow)
{
    __shared__ float lsh[N_NODES];
    __shared__ float red[8];
    const int i = blockIdx.x, t = threadIdx.x;
    const float s1v = s1[i];
    const int* arow = adj + (size_t)i * N_NODES;
    float mx = -3.0e38f;
    for (int j = t; j < N_NODES; j += 256) {
        float l = (arow[j] > 0) ? actf<ACT>(s1v + s2[j]) : NEGV;
        lsh[j] = l;
        mx = fmaxf(mx, l);
    }
    mx = waveReduceMax(mx);
    if ((t & 63) == 0) red[t >> 6] = mx;
    __syncthreads();
    float M = fmaxf(fmaxf(red[0], red[1]), fmaxf(red[2], red[3]));
    float sum = 0.f;
    for (int j = t; j < N_NODES; j += 256) sum += expf(lsh[j] - M);
    sum = waveReduceSum(sum);
    if ((t & 63) == 0) red[4 + (t >> 6)] = sum;
    __syncthreads();
    if (t == 0) {
        float Z = red[4] + red[5] + red[6] + red[7];
        mrow[i] = M;
        rrow[i] = 1.f / Z;
    }
}

// ---------------- fused att @ h ----------------
// out tile 64x128 per block; att weights regenerated on the fly from s1,s2,m,r,adj.
// MODE 0: out = 0.99*acc + 0.01*h   (GAT)
// MODE 1: out = acc                  (core head 0)
// MODE 2: out += acc                 (core heads 1..3)
template<int MODE, int ACT>
__global__ __launch_bounds__(256)
void att_apply(const float* __restrict__ hsrc, const float* __restrict__ s1,
               const float* __restrict__ s2, const float* __restrict__ mrow,
               const float* __restrict__ rrow, const int* __restrict__ adj,
               float* __restrict__ out, int Nc)
{
    __shared__ float Ws[64][68];    // [jj][i_local], padded (f4-aligned rows)
    __shared__ float Hs[64][132];   // [jj][c_local], padded
    const int t  = threadIdx.x;
    const int i0 = blockIdx.x * 64;
    const int c0 = blockIdx.y * 128;
    const int rg = t >> 4, cg = t & 15;
    const int iL = t & 63, jq = t >> 6;
    const float s1v = s1[i0 + iL];
    const float mv  = mrow[i0 + iL];
    const float rv  = rrow[i0 + iL];
    float acc[4][8] = {};

    for (int j0 = 0; j0 < N_NODES; j0 += 64) {
        // phase 1: softmax weights for this 64x64 tile
        #pragma unroll
        for (int stepj = 0; stepj < 16; ++stepj) {
            int jj = jq + (stepj << 2);
            int j  = j0 + jj;
            float w = 0.f;
            if (adj[(size_t)(i0 + iL) * N_NODES + j] > 0) {
                float l = actf<ACT>(s1v + s2[j]);
                w = expf(l - mv) * rv;
            }
            Ws[jj][iL] = w;
        }
        // phase 2: stage h[j0:j0+64, c0:c0+128]
        {
            int cc4 = (t & 31) << 2;
            int jb  = t >> 5;
            #pragma unroll
            for (int p = 0; p < 8; ++p) {
                int jj = jb + (p << 3);
                float4 v = *(const float4*)(hsrc + (size_t)(j0 + jj) * Nc + c0 + cc4);
                *(float4*)&Hs[jj][cc4] = v;
            }
        }
        __syncthreads();
        // phase 3: rank-64 update of the 64x128 tile
        #pragma unroll 8
        for (int jj = 0; jj < 64; ++jj) {
            float4 w4 = *(const float4*)&Ws[jj][rg << 2];
            float4 h0 = *(const float4*)&Hs[jj][cg << 3];
            float4 h1 = *(const float4*)&Hs[jj][(cg << 3) + 4];
            float wa[4] = {w4.x, w4.y, w4.z, w4.w};
            float hb[8] = {h0.x, h0.y, h0.z, h0.w, h1.x, h1.y, h1.z, h1.w};
            #pragma unroll
            for (int a = 0; a < 4; ++a)
                #pragma unroll
                for (int b = 0; b < 8; ++b)
                    acc[a][b] += wa[a] * hb[b];
        }
        __syncthreads();
    }
    #pragma unroll
    for (int a = 0; a < 4; ++a) {
        int row = i0 + (rg << 2) + a;
        float* op = out + (size_t)row * Nc + c0 + (cg << 3);
        const float* hp = hsrc + (size_t)row * Nc + c0 + (cg << 3);
        #pragma unroll
        for (int b = 0; b < 8; ++b) {
            float v = acc[a][b];
            if (MODE == 0) v = 0.99f * v + 0.01f * hp[b];
            else if (MODE == 2) v += op[b];
            op[b] = v;
        }
    }
}

// ---------------- GAT epilogue: xacc (+)= l2norm_rows(elu(gout)) + b ----------------
template<int FIRST>
__global__ __launch_bounds__(128)
void gat_post(const float* __restrict__ gout, const float* __restrict__ bias,
              float* __restrict__ xacc)
{
    __shared__ float red[2];
    const int i = blockIdx.x, t = threadIdx.x;
    const float* gp = gout + (size_t)i * H1;
    float g[3]; float ss = 0.f;
    #pragma unroll
    for (int u = 0; u < 3; ++u) {
        float v = eluf(gp[t + u * 128]);
        g[u] = v; ss += v * v;
    }
    ss = waveReduceSum(ss);
    if ((t & 63) == 0) red[t >> 6] = ss;
    __syncthreads();
    float inv = 1.f / fmaxf(sqrtf(red[0] + red[1]), 1e-12f);
    float* xp = xacc + (size_t)i * H1;
    #pragma unroll
    for (int u = 0; u < 3; ++u) {
        int c = t + u * 128;
        float val = g[u] * inv + bias[c];
        if (FIRST) xp[c] = val; else xp[c] += val;
    }
}

// ---------------- conv(K=129, 3 ch) + elu + channel-combine -> hcore ----------------
__global__ __launch_bounds__(256)
void conv_combine(const float* __restrict__ xacc, const float* __restrict__ w_mid,
                  const float* __restrict__ b_mid, const float* __restrict__ w_core,
                  const float* __restrict__ b_core, float* __restrict__ hcore)
{
    __shared__ float row[H1];
    __shared__ float wm[3 * K_MID];
    const int n = blockIdx.x, t = threadIdx.x;
    for (int k = t; k < H1; k += 256) row[k] = eluf(xacc[(size_t)n * H1 + k] * (1.f / 3.f));
    for (int k = t; k < 3 * K_MID; k += 256) wm[k] = w_mid[k];
    __syncthreads();
    const int w = t;  // 0..255 = H2
    float a0 = 0.f, a1 = 0.f, a2 = 0.f;
    for (int k = 0; k < K_MID; ++k) {
        float xv = row[w + k];
        a0 += xv * wm[k];
        a1 += xv * wm[K_MID + k];
        a2 += xv * wm[2 * K_MID + k];
    }
    float hv = eluf(a0 + b_mid[0]) * w_core[0]
             + eluf(a1 + b_mid[1]) * w_core[1]
             + eluf(a2 + b_mid[2]) * w_core[2] + b_core[0];
    hcore[(size_t)n * H2 + w] = hv;
}

// ---------------- core epilogue: embed = l2norm(elu(0.5*hpass/4 + 0.5*h)) + cbias ----------------
__global__ __launch_bounds__(256)
void core_post(const float* __restrict__ hpass, const float* __restrict__ hcore,
               const float* __restrict__ cbias, float* __restrict__ embed)
{
    __shared__ float red[4];
    const int i = blockIdx.x, t = threadIdx.x;
    float hv = hcore[(size_t)i * H2 + t];
    float v = eluf(0.5f * (hpass[(size_t)i * H2 + t] * 0.25f) + 0.5f * hv);
    float ss = waveReduceSum(v * v);
    if ((t & 63) == 0) red[t >> 6] = ss;
    __syncthreads();
    float inv = 1.f / fmaxf(sqrtf(red[0] + red[1] + red[2] + red[3]), 1e-12f);
    embed[(size_t)i * H2 + t] = v * inv + cbias[t];
}

// ---------------- pred[e] = tf[src[e]] . tg[dst[e]] ----------------
__global__ __launch_bounds__(256)
void gather_dot(const float* __restrict__ tf, const float* __restrict__ tg,
                const int* __restrict__ ts, float* __restrict__ pred)
{
    const int e = blockIdx.x * 4 + (threadIdx.x >> 6);
    const int lane = threadIdx.x & 63;
    const int i0 = ts[(size_t)e * 2], i1 = ts[(size_t)e * 2 + 1];
    const float* a = tf + (size_t)i0 * D_OUT;
    const float* b = tg + (size_t)i1 * D_OUT;
    float p = a[lane] * b[lane] + a[lane + 64] * b[lane + 64];
    p = waveReduceSum(p);
    if (lane == 0) pred[e] = p;
}

// ---------------- launch ----------------
extern "C" void kernel_launch(void* const* d_in, const int* in_sizes, int n_in,
                              void* d_out, int out_size, void* d_ws, size_t ws_size,
                              hipStream_t stream)
{
    const float* x[3]   = {(const float*)d_in[0], (const float*)d_in[1], (const float*)d_in[2]};
    const int*   adj    = (const int*)d_in[3];
    const int*   ts     = (const int*)d_in[4];
    const float* gat_W  = (const float*)d_in[5];
    const float* gat_a  = (const float*)d_in[6];
    const float* gat_b  = (const float*)d_in[7];
    const float* w_mid  = (const float*)d_in[8];
    const float* b_mid  = (const float*)d_in[9];
    const float* w_core = (const float*)d_in[10];
    const float* b_core = (const float*)d_in[11];
    const float* a_core = (const float*)d_in[12];
    const float* cbias  = (const float*)d_in[13];
    const float* W_tf1  = (const float*)d_in[14];
    const float* b_tf1  = (const float*)d_in[15];
    const float* W_tf2  = (const float*)d_in[16];
    const float* b_tf2  = (const float*)d_in[17];
    const float* W_tg1  = (const float*)d_in[18];
    const float* b_tg1  = (const float*)d_in[19];
    const float* W_tg2  = (const float*)d_in[20];
    const float* b_tg2  = (const float*)d_in[21];

    float* ws    = (float*)d_ws;           // ~44 MB total
    float* h_ws  = ws;
    float* gout  = h_ws  + (size_t)N_NODES * H1;
    float* xacc  = gout  + (size_t)N_NODES * H1;
    float* hcore = xacc  + (size_t)N_NODES * H1;
    float* hpass = hcore + (size_t)N_NODES * H2;
    float* embed = hpass + (size_t)N_NODES * H2;
    float* t1    = embed + (size_t)N_NODES * H2;
    float* tf    = t1    + (size_t)N_NODES * H3;
    float* tg    = tf    + (size_t)N_NODES * D_OUT;
    float* s1    = tg    + (size_t)N_NODES * D_OUT;
    float* s2    = s1 + N_NODES;
    float* mrow  = s2 + N_NODES;
    float* rrow  = mrow + N_NODES;
    float* pred  = (float*)d_out;

    const dim3 blk(256);

    // ---- stage 1: 3 GAT channels ----
    for (int c = 0; c < 3; ++c) {
        gemm_f32<0><<<dim3(N_NODES / 64, H1 / 128), blk, 0, stream>>>(
            x[c], gat_W + (size_t)c * D_IN * H1, nullptr, h_ws, N_NODES, D_IN, H1);
        rowdot2<<<dim3(N_NODES), dim3(64), 0, stream>>>(
            h_ws, gat_a + (size_t)c * 2 * H1, H1, s1, s2);
        softmax_stats<0><<<dim3(N_NODES), blk, 0, stream>>>(s1, s2, adj, mrow, rrow);
        att_apply<0, 0><<<dim3(N_NODES / 64, H1 / 128), blk, 0, stream>>>(
            h_ws, s1, s2, mrow, rrow, adj, gout, H1);
        if (c == 0)
            gat_post<1><<<dim3(N_NODES), dim3(128), 0, stream>>>(gout, gat_b + (size_t)c * H1, xacc);
        else
            gat_post<0><<<dim3(N_NODES), dim3(128), 0, stream>>>(gout, gat_b + (size_t)c * H1, xacc);
    }

    // ---- stage 2: conv + combine ----
    conv_combine<<<dim3(N_NODES), blk, 0, stream>>>(xacc, w_mid, b_mid, w_core, b_core, hcore);

    // ---- stage 3: 4 core heads ----
    for (int hd = 0; hd < 4; ++hd) {
        rowdot2<<<dim3(N_NODES), dim3(64), 0, stream>>>(
            hcore, a_core + (size_t)hd * 2 * H2, H2, s1, s2);
        softmax_stats<1><<<dim3(N_NODES), blk, 0, stream>>>(s1, s2, adj, mrow, rrow);
        if (hd == 0)
            att_apply<1, 1><<<dim3(N_NODES / 64, H2 / 128), blk, 0, stream>>>(
                hcore, s1, s2, mrow, rrow, adj, hpass, H2);
        else
            att_apply<2, 1><<<dim3(N_NODES / 64, H2 / 128), blk, 0, stream>>>(
                hcore, s1, s2, mrow, rrow, adj, hpass, H2);
    }
    core_post<<<dim3(N_NODES), blk, 0, stream>>>(hpass, hcore, cbias, embed);

    // ---- stage 4: final MLPs + edge dots ----
    gemm_f32<1><<<dim3(N_NODES / 64, H3 / 128), blk, 0, stream>>>(embed, W_tf1, b_tf1, t1, N_NODES, H2, H3);
    gemm_f32<1><<<dim3(N_NODES / 64, D_OUT / 128), blk, 0, stream>>>(t1, W_tf2, b_tf2, tf, N_NODES, H3, D_OUT);
    gemm_f32<1><<<dim3(N_NODES / 64, H3 / 128), blk, 0, stream>>>(embed, W_tg1, b_tg1, t1, N_NODES, H2, H3);
    gemm_f32<1><<<dim3(N_NODES / 64, D_OUT / 128), blk, 0, stream>>>(t1, W_tg2, b_tg2, tg, N_NODES, H3, D_OUT);
    gather_dot<<<dim3(E_EDGES / 4), blk, 0, stream>>>(tf, tg, ts, pred);
}

// Round 2
// 2449.932 us; speedup vs baseline: 1.9564x; 1.9564x over previous
//
#include <hip/hip_runtime.h>
#include <math.h>

// ---------------- constants (match reference) ----------------
#define N_NODES 4096
#define D_IN    768
#define H1      384
#define H2      256
#define H3      512
#define D_OUT   128
#define E_EDGES 8192
#define K_MID   129
#define ALPHA   0.2f
#define NEGV    -9000000000000000.0f

typedef unsigned long long u64;

// ---------------- helpers ----------------
__device__ __forceinline__ float eluf(float x) {
    return x > 0.f ? x : expm1f(x);
}

template<int ACT>  // 0 = leaky_relu(0.2), 1 = elu
__device__ __forceinline__ float actf(float x) {
    if (ACT == 0) return x >= 0.f ? x : ALPHA * x;
    else          return x > 0.f ? x : expm1f(x);
}

__device__ __forceinline__ float waveReduceMax(float v) {
    #pragma unroll
    for (int off = 32; off; off >>= 1) v = fmaxf(v, __shfl_xor(v, off));
    return v;
}
__device__ __forceinline__ float waveReduceSum(float v) {
    #pragma unroll
    for (int off = 32; off; off >>= 1) v += __shfl_xor(v, off);
    return v;
}

// ---------------- zero fill ----------------
__global__ __launch_bounds__(256)
void zero_f32(float4* __restrict__ p, int n4) {
    int idx = blockIdx.x * 256 + threadIdx.x;
    int stride = gridDim.x * 256;
    float4 z = {0.f, 0.f, 0.f, 0.f};
    for (int i = idx; i < n4; i += stride) p[i] = z;
}

// ---------------- pack adj into bitmask: bits[i*64 + jw] bit c = adj[i][jw*64+c]>0 ----------------
__global__ __launch_bounds__(256)
void pack_adj(const int* __restrict__ adj, u64* __restrict__ bits, int nwords) {
    int wid  = (blockIdx.x * 256 + threadIdx.x) >> 6;
    int lane = threadIdx.x & 63;
    int nw   = (gridDim.x * 256) >> 6;
    for (int w = wid; w < nwords; w += nw) {
        u64 m = __ballot(adj[((size_t)w << 6) + lane] > 0);
        if (lane == 0) bits[w] = m;
    }
}

// ---------------- batched GEMM: C[z] = act(A[z]@B[z] + bias[z]) ----------------
struct GP {
    const float* A[3];
    const float* B[3];
    const float* bias[3];
    float* C[3];
};

// Tile 64x128, 256 threads, 4x8 per thread, BK=16.  M%64==0, Nc%128==0, K%16==0.
template<int ACT>  // 0: none, 1: elu(v + bias[c])
__global__ __launch_bounds__(256)
void gemm_f32(GP gp, int M, int K, int Nc)
{
    __shared__ float As[16][68];    // [k][i]
    __shared__ float Bs[16][132];   // [k][c]
    const int z = blockIdx.z;
    const float* __restrict__ A    = gp.A[z];
    const float* __restrict__ B    = gp.B[z];
    const float* __restrict__ bias = gp.bias[z];
    float* __restrict__ C          = gp.C[z];

    const int t  = threadIdx.x;
    const int i0 = blockIdx.x * 64;
    const int c0 = blockIdx.y * 128;
    const int rg = t >> 4;          // 0..15 -> rows rg*4..+3
    const int cg = t & 15;          // cols {c0+4cg..+3} and {c0+64+4cg..+3}
    float acc[4][8] = {};

    for (int k0 = 0; k0 < K; k0 += 16) {
        {   // A tile 64x16
            int i = t & 63, kq = t >> 6;
            float4 v = *(const float4*)(A + (size_t)(i0 + i) * K + k0 + (kq << 2));
            As[(kq << 2) + 0][i] = v.x;
            As[(kq << 2) + 1][i] = v.y;
            As[(kq << 2) + 2][i] = v.z;
            As[(kq << 2) + 3][i] = v.w;
        }
        {   // B tile 16x128
            int kb = t >> 5, cc4 = (t & 31) << 2;
            #pragma unroll
            for (int p = 0; p < 2; ++p) {
                int k = kb + (p << 3);
                *(float4*)&Bs[k][cc4] = *(const float4*)(B + (size_t)(k0 + k) * Nc + c0 + cc4);
            }
        }
        __syncthreads();
        #pragma unroll
        for (int k = 0; k < 16; ++k) {
            float4 a4 = *(const float4*)&As[k][rg << 2];
            float4 b0 = *(const float4*)&Bs[k][cg << 2];
            float4 b1 = *(const float4*)&Bs[k][64 + (cg << 2)];
            float wa[4] = {a4.x, a4.y, a4.z, a4.w};
            float hb[8] = {b0.x, b0.y, b0.z, b0.w, b1.x, b1.y, b1.z, b1.w};
            #pragma unroll
            for (int a = 0; a < 4; ++a)
                #pragma unroll
                for (int b = 0; b < 8; ++b)
                    acc[a][b] += wa[a] * hb[b];
        }
        __syncthreads();
    }
    const int colA = c0 + (cg << 2);
    #pragma unroll
    for (int a = 0; a < 4; ++a) {
        int row = i0 + (rg << 2) + a;
        float r0[4], r1[4];
        #pragma unroll
        for (int b = 0; b < 4; ++b) {
            float v0 = acc[a][b], v1 = acc[a][b + 4];
            if (ACT == 1) {
                v0 = eluf(v0 + bias[colA + b]);
                v1 = eluf(v1 + bias[colA + 64 + b]);
            }
            r0[b] = v0; r1[b] = v1;
        }
        *(float4*)&C[(size_t)row * Nc + colA]      = *(float4*)r0;
        *(float4*)&C[(size_t)row * Nc + colA + 64] = *(float4*)r1;
    }
}

// ---------------- batched row dots: s1[z][i]=h_z[i,:]@a_z[0:K], s2 likewise ----------------
__global__ __launch_bounds__(64)
void rowdot2(const float* __restrict__ hbase, size_t hStride,
             const float* __restrict__ ab, int K,
             float* __restrict__ s1b, float* __restrict__ s2b)
{
    const int i = blockIdx.x, z = blockIdx.y, lane = threadIdx.x;
    const float* hp = hbase + (size_t)z * hStride + (size_t)i * K;
    const float* a  = ab + (size_t)z * 2 * K;
    float p1 = 0.f, p2 = 0.f;
    for (int k = lane; k < K; k += 64) {
        float hv = hp[k];
        p1 += hv * a[k];
        p2 += hv * a[K + k];
    }
    p1 = waveReduceSum(p1);
    p2 = waveReduceSum(p2);
    if (lane == 0) { s1b[z * N_NODES + i] = p1; s2b[z * N_NODES + i] = p2; }
}

// ---------------- per-row softmax stats: q[z][i] = M + ln(Z)  (w = exp(l - q)) ----------------
template<int ACT>
__global__ __launch_bounds__(256)
void softmax_stats(const float* __restrict__ s1b, const float* __restrict__ s2b,
                   const u64* __restrict__ bits, float* __restrict__ qb)
{
    __shared__ float lsh[N_NODES];
    __shared__ float red[8];
    const int i = blockIdx.x, z = blockIdx.y, t = threadIdx.x;
    const float s1v = s1b[z * N_NODES + i];
    const float* s2 = s2b + (size_t)z * N_NODES;
    float mx = -3.0e38f;
    for (int j = t; j < N_NODES; j += 256) {
        u64 wd = bits[((size_t)i << 6) + (j >> 6)];
        float l = ((wd >> (j & 63)) & 1ull) ? actf<ACT>(s1v + s2[j]) : NEGV;
        lsh[j] = l;
        mx = fmaxf(mx, l);
    }
    mx = waveReduceMax(mx);
    if ((t & 63) == 0) red[t >> 6] = mx;
    __syncthreads();
    float M = fmaxf(fmaxf(red[0], red[1]), fmaxf(red[2], red[3]));
    float sum = 0.f;
    for (int j = t; j < N_NODES; j += 256) sum += expf(lsh[j] - M);
    sum = waveReduceSum(sum);
    if ((t & 63) == 0) red[4 + (t >> 6)] = sum;
    __syncthreads();
    if (t == 0) {
        float Z = red[4] + red[5] + red[6] + red[7];
        qb[z * N_NODES + i] = M + logf(Z);
    }
}

// ---------------- fused (Σ_heads att) @ h with j-split + atomic accumulate ----------------
// MODE 0: atomicAdd(out, 0.99*acc)  (GAT; gat_post adds 0.01*h)
// MODE 1: atomicAdd(out, acc)       (core; core_post scales by 0.25)
template<int MODE, int ACT, int NH>
__global__ __launch_bounds__(256)
void att_apply(const float* __restrict__ h, const float* __restrict__ s1b,
               const float* __restrict__ s2b, const float* __restrict__ qb,
               const u64* __restrict__ bits, float* __restrict__ out,
               int Nc, int nJt)
{
    __shared__ float Ws[64][68];    // [jj][iL]
    __shared__ float Hs[64][132];   // [jj][cL]
    const int t  = threadIdx.x;
    const int i0 = blockIdx.x * 64;
    const int c0 = blockIdx.y * 128;
    const int rg = t >> 4, cg = t & 15;
    const int c  = t & 63, wv = t >> 6;
    const int jt0 = blockIdx.z * nJt;
    float acc[4][8] = {};

    for (int jt = jt0; jt < jt0 + nJt; ++jt) {
        const int j0 = jt << 6;
        // phase 1: combined softmax weights for this 64x64 tile (lane = j, coalesced)
        #pragma unroll
        for (int rr = 0; rr < 16; ++rr) {
            const int iL = (rr << 2) | wv;   // wave-uniform row
            const int i  = i0 + iL;
            u64 wd = bits[((size_t)i << 6) + jt];
            float w = 0.f;
            if ((wd >> c) & 1ull) {
                #pragma unroll
                for (int hd = 0; hd < NH; ++hd) {
                    float l = actf<ACT>(s1b[hd * N_NODES + i] + s2b[hd * N_NODES + j0 + c]);
                    w += expf(l - qb[hd * N_NODES + i]);
                }
            }
            Ws[c][iL] = w;
        }
        // phase 2: stage h[j0:j0+64, c0:c0+128]
        {
            const int cc4 = (t & 31) << 2;
            const int jb  = t >> 5;
            #pragma unroll
            for (int p = 0; p < 8; ++p) {
                const int jj = jb + (p << 3);
                *(float4*)&Hs[jj][cc4] =
                    *(const float4*)(h + (size_t)(j0 + jj) * Nc + c0 + cc4);
            }
        }
        __syncthreads();
        // phase 3: rank-64 update
        #pragma unroll 4
        for (int jj = 0; jj < 64; ++jj) {
            float4 w4  = *(const float4*)&Ws[jj][rg << 2];
            float4 h0v = *(const float4*)&Hs[jj][cg << 2];
            float4 h1v = *(const float4*)&Hs[jj][64 + (cg << 2)];
            float wa[4] = {w4.x, w4.y, w4.z, w4.w};
            float hb[8] = {h0v.x, h0v.y, h0v.z, h0v.w, h1v.x, h1v.y, h1v.z, h1v.w};
            #pragma unroll
            for (int a = 0; a < 4; ++a)
                #pragma unroll
                for (int b = 0; b < 8; ++b)
                    acc[a][b] += wa[a] * hb[b];
        }
        __syncthreads();
    }
    const float scale = (MODE == 0) ? 0.99f : 1.f;
    const int colA = c0 + (cg << 2);
    #pragma unroll
    for (int a = 0; a < 4; ++a) {
        int row = i0 + (rg << 2) + a;
        float* op = out + (size_t)row * Nc;
        #pragma unroll
        for (int b = 0; b < 4; ++b) {
            unsafeAtomicAdd(op + colA + b,      scale * acc[a][b]);
            unsafeAtomicAdd(op + colA + 64 + b, scale * acc[a][b + 4]);
        }
    }
}

// ---------------- GAT epilogue: xacc (+)= l2norm_rows(elu(gacc + 0.01h)) + b ----------------
template<int FIRST>
__global__ __launch_bounds__(128)
void gat_post(const float* __restrict__ gacc, const float* __restrict__ h,
              const float* __restrict__ bias, float* __restrict__ xacc)
{
    __shared__ float red[2];
    const int i = blockIdx.x, t = threadIdx.x;
    const float* gp = gacc + (size_t)i * H1;
    const float* hp = h    + (size_t)i * H1;
    float g[3]; float ss = 0.f;
    #pragma unroll
    for (int u = 0; u < 3; ++u) {
        int cidx = t + u * 128;
        float v = eluf(gp[cidx] + 0.01f * hp[cidx]);
        g[u] = v; ss += v * v;
    }
    ss = waveReduceSum(ss);
    if ((t & 63) == 0) red[t >> 6] = ss;
    __syncthreads();
    float inv = 1.f / fmaxf(sqrtf(red[0] + red[1]), 1e-12f);
    float* xp = xacc + (size_t)i * H1;
    #pragma unroll
    for (int u = 0; u < 3; ++u) {
        int cidx = t + u * 128;
        float val = g[u] * inv + bias[cidx];
        if (FIRST) xp[cidx] = val; else xp[cidx] += val;
    }
}

// ---------------- conv(K=129, 3 ch) + elu + channel-combine -> hcore ----------------
__global__ __launch_bounds__(256)
void conv_combine(const float* __restrict__ xacc, const float* __restrict__ w_mid,
                  const float* __restrict__ b_mid, const float* __restrict__ w_core,
                  const float* __restrict__ b_core, float* __restrict__ hcore)
{
    __shared__ float row[H1];
    __shared__ float wm[3 * K_MID];
    const int n = blockIdx.x, t = threadIdx.x;
    for (int k = t; k < H1; k += 256) row[k] = eluf(xacc[(size_t)n * H1 + k] * (1.f / 3.f));
    for (int k = t; k < 3 * K_MID; k += 256) wm[k] = w_mid[k];
    __syncthreads();
    const int w = t;  // 0..255 = H2
    float a0 = 0.f, a1 = 0.f, a2 = 0.f;
    for (int k = 0; k < K_MID; ++k) {
        float xv = row[w + k];
        a0 += xv * wm[k];
        a1 += xv * wm[K_MID + k];
        a2 += xv * wm[2 * K_MID + k];
    }
    float hv = eluf(a0 + b_mid[0]) * w_core[0]
             + eluf(a1 + b_mid[1]) * w_core[1]
             + eluf(a2 + b_mid[2]) * w_core[2] + b_core[0];
    hcore[(size_t)n * H2 + w] = hv;
}

// ---------------- core epilogue ----------------
__global__ __launch_bounds__(256)
void core_post(const float* __restrict__ hpass, const float* __restrict__ hcore,
               const float* __restrict__ cbias, float* __restrict__ embed)
{
    __shared__ float red[4];
    const int i = blockIdx.x, t = threadIdx.x;
    float hv = hcore[(size_t)i * H2 + t];
    float v = eluf(0.5f * (hpass[(size_t)i * H2 + t] * 0.25f) + 0.5f * hv);
    float ss = waveReduceSum(v * v);
    if ((t & 63) == 0) red[t >> 6] = ss;
    __syncthreads();
    float inv = 1.f / fmaxf(sqrtf(red[0] + red[1] + red[2] + red[3]), 1e-12f);
    embed[(size_t)i * H2 + t] = v * inv + cbias[t];
}

// ---------------- pred[e] = tf[src[e]] . tg[dst[e]] ----------------
__global__ __launch_bounds__(256)
void gather_dot(const float* __restrict__ tf, const float* __restrict__ tg,
                const int* __restrict__ ts, float* __restrict__ pred)
{
    const int e = blockIdx.x * 4 + (threadIdx.x >> 6);
    const int lane = threadIdx.x & 63;
    const int i0 = ts[(size_t)e * 2], i1 = ts[(size_t)e * 2 + 1];
    const float* a = tf + (size_t)i0 * D_OUT;
    const float* b = tg + (size_t)i1 * D_OUT;
    float p = a[lane] * b[lane] + a[lane + 64] * b[lane + 64];
    p = waveReduceSum(p);
    if (lane == 0) pred[e] = p;
}

// ---------------- launch ----------------
extern "C" void kernel_launch(void* const* d_in, const int* in_sizes, int n_in,
                              void* d_out, int out_size, void* d_ws, size_t ws_size,
                              hipStream_t stream)
{
    const float* x1     = (const float*)d_in[0];
    const float* x2     = (const float*)d_in[1];
    const float* x3     = (const float*)d_in[2];
    const int*   adj    = (const int*)d_in[3];
    const int*   ts     = (const int*)d_in[4];
    const float* gat_W  = (const float*)d_in[5];
    const float* gat_a  = (const float*)d_in[6];
    const float* gat_b  = (const float*)d_in[7];
    const float* w_mid  = (const float*)d_in[8];
    const float* b_mid  = (const float*)d_in[9];
    const float* w_core = (const float*)d_in[10];
    const float* b_core = (const float*)d_in[11];
    const float* a_core = (const float*)d_in[12];
    const float* cbias  = (const float*)d_in[13];
    const float* W_tf1  = (const float*)d_in[14];
    const float* b_tf1  = (const float*)d_in[15];
    const float* W_tf2  = (const float*)d_in[16];
    const float* b_tf2  = (const float*)d_in[17];
    const float* W_tg1  = (const float*)d_in[18];
    const float* b_tg1  = (const float*)d_in[19];
    const float* W_tg2  = (const float*)d_in[20];
    const float* b_tg2  = (const float*)d_in[21];

    // ---- workspace layout (floats) ----
    const int NWORDS = N_NODES * (N_NODES / 64);        // 262144 u64
    u64*   bits = (u64*)d_ws;
    float* fw   = (float*)d_ws;
    size_t off  = (size_t)NWORDS * 2;                   // u64 = 2 floats
    float* s1b  = fw + off;  off += 4 * (size_t)N_NODES;
    float* s2b  = fw + off;  off += 4 * (size_t)N_NODES;
    float* qb   = fw + off;  off += 4 * (size_t)N_NODES;
    float* pool = fw + off;
    const size_t HSZ = (size_t)N_NODES * H1;            // 1572864
    float* h0    = pool;                    // 3 GAT h buffers (contiguous)
    float* gout  = pool + 3 * HSZ;
    float* xacc  = pool + 4 * HSZ;
    // aliases (stage 2+; h0..h2/gout/xacc free by then)
    float* hcore = h0;                                   // N*H2
    float* hpass = pool + 1 * HSZ;                       // N*H2
    float* embed = pool + 2 * HSZ;                       // N*H2
    float* t1f   = pool + 3 * HSZ;                       // N*H3 (spans gout+part of xacc)
    float* t1g   = t1f + (size_t)N_NODES * H3;
    float* tf    = t1g + (size_t)N_NODES * H3;
    float* tg    = tf  + (size_t)N_NODES * D_OUT;
    float* pred  = (float*)d_out;

    const dim3 blk(256);

    // ---- adj -> bitmask ----
    pack_adj<<<dim3(1024), blk, 0, stream>>>(adj, bits, NWORDS);

    // ---- stage 1: 3 GAT channels ----
    {   // batched h_c = x_c @ W_c
        GP gp;
        gp.A[0] = x1; gp.A[1] = x2; gp.A[2] = x3;
        for (int c = 0; c < 3; ++c) {
            gp.B[c]    = gat_W + (size_t)c * D_IN * H1;
            gp.bias[c] = nullptr;
            gp.C[c]    = h0 + (size_t)c * HSZ;
        }
        gemm_f32<0><<<dim3(N_NODES / 64, H1 / 128, 3), blk, 0, stream>>>(gp, N_NODES, D_IN, H1);
    }
    rowdot2<<<dim3(N_NODES, 3), dim3(64), 0, stream>>>(h0, HSZ, gat_a, H1, s1b, s2b);
    softmax_stats<0><<<dim3(N_NODES, 3), blk, 0, stream>>>(s1b, s2b, bits, qb);
    for (int c = 0; c < 3; ++c) {
        float* hc = h0 + (size_t)c * HSZ;
        zero_f32<<<dim3(768), blk, 0, stream>>>((float4*)gout, (int)(HSZ / 4));
        att_apply<0, 0, 1><<<dim3(N_NODES / 64, H1 / 128, 4), blk, 0, stream>>>(
            hc, s1b + (size_t)c * N_NODES, s2b + (size_t)c * N_NODES,
            qb + (size_t)c * N_NODES, bits, gout, H1, 16);
        if (c == 0)
            gat_post<1><<<dim3(N_NODES), dim3(128), 0, stream>>>(gout, hc, gat_b + (size_t)c * H1, xacc);
        else
            gat_post<0><<<dim3(N_NODES), dim3(128), 0, stream>>>(gout, hc, gat_b + (size_t)c * H1, xacc);
    }

    // ---- stage 2: conv + combine ----
    conv_combine<<<dim3(N_NODES), blk, 0, stream>>>(xacc, w_mid, b_mid, w_core, b_core, hcore);

    // ---- stage 3: 4 core heads, collapsed: hpass = (Σ_hd att_hd) @ hcore ----
    rowdot2<<<dim3(N_NODES, 4), dim3(64), 0, stream>>>(hcore, 0, a_core, H2, s1b, s2b);
    softmax_stats<1><<<dim3(N_NODES, 4), blk, 0, stream>>>(s1b, s2b, bits, qb);
    zero_f32<<<dim3(768), blk, 0, stream>>>((float4*)hpass, (int)((size_t)N_NODES * H2 / 4));
    att_apply<1, 1, 4><<<dim3(N_NODES / 64, H2 / 128, 8), blk, 0, stream>>>(
        hcore, s1b, s2b, qb, bits, hpass, H2, 8);
    core_post<<<dim3(N_NODES), blk, 0, stream>>>(hpass, hcore, cbias, embed);

    // ---- stage 4: final MLPs (tf/tg batched) + edge dots ----
    {
        GP gp;
        gp.A[0] = embed; gp.A[1] = embed; gp.A[2] = embed;
        gp.B[0] = W_tf1; gp.B[1] = W_tg1; gp.B[2] = W_tg1;
        gp.bias[0] = b_tf1; gp.bias[1] = b_tg1; gp.bias[2] = b_tg1;
        gp.C[0] = t1f; gp.C[1] = t1g; gp.C[2] = t1g;
        gemm_f32<1><<<dim3(N_NODES / 64, H3 / 128, 2), blk, 0, stream>>>(gp, N_NODES, H2, H3);
    }
    {
        GP gp;
        gp.A[0] = t1f; gp.A[1] = t1g; gp.A[2] = t1g;
        gp.B[0] = W_tf2; gp.B[1] = W_tg2; gp.B[2] = W_tg2;
        gp.bias[0] = b_tf2; gp.bias[1] = b_tg2; gp.bias[2] = b_tg2;
        gp.C[0] = tf; gp.C[1] = tg; gp.C[2] = tg;
        gemm_f32<1><<<dim3(N_NODES / 64, D_OUT / 128, 2), blk, 0, stream>>>(gp, N_NODES, H3, D_OUT);
    }
    gather_dot<<<dim3(E_EDGES / 4), blk, 0, stream>>>(tf, tg, ts, pred);
}

// Round 3
// 924.529 us; speedup vs baseline: 5.1843x; 2.6499x over previous
//
#include <hip/hip_runtime.h>
#include <math.h>

// ---------------- constants (match reference) ----------------
#define N_NODES 4096
#define D_IN    768
#define H1      384
#define H2      256
#define H3      512
#define D_OUT   128
#define E_EDGES 8192
#define K_MID   129
#define ALPHA   0.2f
#define NEGV    -9000000000000000.0f

typedef unsigned long long u64;
typedef unsigned short u16;
typedef __attribute__((ext_vector_type(8))) short bf16x8;
typedef __attribute__((ext_vector_type(4))) float f32x4;

// ---------------- helpers ----------------
__device__ __forceinline__ float eluf(float x) {          // precise (epilogues)
    return x > 0.f ? x : expm1f(x);
}

template<int ACT>  // 0 = leaky_relu(0.2), 1 = elu  (fast path, softmax logits)
__device__ __forceinline__ float actf(float x) {
    if (ACT == 0) return x >= 0.f ? x : ALPHA * x;
    else          return x > 0.f ? x : __expf(x) - 1.f;
}

__device__ __forceinline__ u16 f2bf(float f) {            // RNE fp32 -> bf16 bits
    unsigned u = __float_as_uint(f);
    unsigned r = (u + 0x7FFFu + ((u >> 16) & 1u)) >> 16;
    return (u16)r;
}

__device__ __forceinline__ float waveReduceMax(float v) {
    #pragma unroll
    for (int off = 32; off; off >>= 1) v = fmaxf(v, __shfl_xor(v, off));
    return v;
}
__device__ __forceinline__ float waveReduceSum(float v) {
    #pragma unroll
    for (int off = 32; off; off >>= 1) v += __shfl_xor(v, off);
    return v;
}

// ---------------- pack adj into bitmask ----------------
__global__ __launch_bounds__(256)
void pack_adj(const int* __restrict__ adj, u64* __restrict__ bits, int nwords) {
    int wid  = (blockIdx.x * 256 + threadIdx.x) >> 6;
    int lane = threadIdx.x & 63;
    int nw   = (gridDim.x * 256) >> 6;
    for (int w = wid; w < nwords; w += nw) {
        u64 m = __ballot(adj[((size_t)w << 6) + lane] > 0);
        if (lane == 0) bits[w] = m;
    }
}

// ---------------- batched fp32 GEMM (unchanged from round 2) ----------------
struct GP {
    const float* A[3];
    const float* B[3];
    const float* bias[3];
    float* C[3];
};

template<int ACT>  // 0: none, 1: elu(v + bias[c])
__global__ __launch_bounds__(256)
void gemm_f32(GP gp, int M, int K, int Nc)
{
    __shared__ float As[16][68];
    __shared__ float Bs[16][132];
    const int z = blockIdx.z;
    const float* __restrict__ A    = gp.A[z];
    const float* __restrict__ B    = gp.B[z];
    const float* __restrict__ bias = gp.bias[z];
    float* __restrict__ C          = gp.C[z];

    const int t  = threadIdx.x;
    const int i0 = blockIdx.x * 64;
    const int c0 = blockIdx.y * 128;
    const int rg = t >> 4;
    const int cg = t & 15;
    float acc[4][8] = {};

    for (int k0 = 0; k0 < K; k0 += 16) {
        {
            int i = t & 63, kq = t >> 6;
            float4 v = *(const float4*)(A + (size_t)(i0 + i) * K + k0 + (kq << 2));
            As[(kq << 2) + 0][i] = v.x;
            As[(kq << 2) + 1][i] = v.y;
            As[(kq << 2) + 2][i] = v.z;
            As[(kq << 2) + 3][i] = v.w;
        }
        {
            int kb = t >> 5, cc4 = (t & 31) << 2;
            #pragma unroll
            for (int p = 0; p < 2; ++p) {
                int k = kb + (p << 3);
                *(float4*)&Bs[k][cc4] = *(const float4*)(B + (size_t)(k0 + k) * Nc + c0 + cc4);
            }
        }
        __syncthreads();
        #pragma unroll
        for (int k = 0; k < 16; ++k) {
            float4 a4 = *(const float4*)&As[k][rg << 2];
            float4 b0 = *(const float4*)&Bs[k][cg << 2];
            float4 b1 = *(const float4*)&Bs[k][64 + (cg << 2)];
            float wa[4] = {a4.x, a4.y, a4.z, a4.w};
            float hb[8] = {b0.x, b0.y, b0.z, b0.w, b1.x, b1.y, b1.z, b1.w};
            #pragma unroll
            for (int a = 0; a < 4; ++a)
                #pragma unroll
                for (int b = 0; b < 8; ++b)
                    acc[a][b] += wa[a] * hb[b];
        }
        __syncthreads();
    }
    const int colA = c0 + (cg << 2);
    #pragma unroll
    for (int a = 0; a < 4; ++a) {
        int row = i0 + (rg << 2) + a;
        float r0[4], r1[4];
        #pragma unroll
        for (int b = 0; b < 4; ++b) {
            float v0 = acc[a][b], v1 = acc[a][b + 4];
            if (ACT == 1) {
                v0 = eluf(v0 + bias[colA + b]);
                v1 = eluf(v1 + bias[colA + 64 + b]);
            }
            r0[b] = v0; r1[b] = v1;
        }
        *(float4*)&C[(size_t)row * Nc + colA]      = *(float4*)r0;
        *(float4*)&C[(size_t)row * Nc + colA + 64] = *(float4*)r1;
    }
}

// ---------------- batched row dots ----------------
__global__ __launch_bounds__(64)
void rowdot2(const float* __restrict__ hbase, size_t hStride,
             const float* __restrict__ ab, int K,
             float* __restrict__ s1b, float* __restrict__ s2b)
{
    const int i = blockIdx.x, z = blockIdx.y, lane = threadIdx.x;
    const float* hp = hbase + (size_t)z * hStride + (size_t)i * K;
    const float* a  = ab + (size_t)z * 2 * K;
    float p1 = 0.f, p2 = 0.f;
    for (int k = lane; k < K; k += 64) {
        float hv = hp[k];
        p1 += hv * a[k];
        p2 += hv * a[K + k];
    }
    p1 = waveReduceSum(p1);
    p2 = waveReduceSum(p2);
    if (lane == 0) { s1b[z * N_NODES + i] = p1; s2b[z * N_NODES + i] = p2; }
}

// ---------------- per-row softmax stats: q[z][i] = M + ln(Z) ----------------
template<int ACT>
__global__ __launch_bounds__(256)
void softmax_stats(const float* __restrict__ s1b, const float* __restrict__ s2b,
                   const u64* __restrict__ bits, float* __restrict__ qb)
{
    __shared__ float lsh[N_NODES];
    __shared__ float red[8];
    const int i = blockIdx.x, z = blockIdx.y, t = threadIdx.x;
    const float s1v = s1b[z * N_NODES + i];
    const float* s2 = s2b + (size_t)z * N_NODES;
    float mx = -3.0e38f;
    for (int j = t; j < N_NODES; j += 256) {
        u64 wd = bits[((size_t)i << 6) + (j >> 6)];
        float l = ((wd >> (j & 63)) & 1ull) ? actf<ACT>(s1v + s2[j]) : NEGV;
        lsh[j] = l;
        mx = fmaxf(mx, l);
    }
    mx = waveReduceMax(mx);
    if ((t & 63) == 0) red[t >> 6] = mx;
    __syncthreads();
    float M = fmaxf(fmaxf(red[0], red[1]), fmaxf(red[2], red[3]));
    float sum = 0.f;
    for (int j = t; j < N_NODES; j += 256) sum += __expf(lsh[j] - M);
    sum = waveReduceSum(sum);
    if ((t & 63) == 0) red[4 + (t >> 6)] = sum;
    __syncthreads();
    if (t == 0) {
        float Z = red[4] + red[5] + red[6] + red[7];
        qb[z * N_NODES + i] = M + logf(Z);
    }
}

// ---------------- transpose + cvt: dst[c][j] = bf16(src[j][c]) ----------------
__global__ __launch_bounds__(256)
void transpose_cvt(const float* __restrict__ src, u16* __restrict__ dst, int C)
{
    __shared__ float tile[64][65];
    const int j0 = blockIdx.x * 64, c0 = blockIdx.y * 64;
    const int t = threadIdx.x;
    #pragma unroll
    for (int q = 0; q < 16; ++q) {
        int idx = q * 256 + t;
        int jl = idx >> 6, cl = idx & 63;
        tile[jl][cl] = src[(size_t)(j0 + jl) * C + c0 + cl];
    }
    __syncthreads();
    #pragma unroll
    for (int q = 0; q < 16; ++q) {
        int idx = q * 256 + t;
        int cl = idx >> 6, jl = idx & 63;
        dst[(size_t)(c0 + cl) * N_NODES + j0 + jl] = f2bf(tile[jl][cl]);
    }
}

// ---------------- MFMA att: partial[z][i][c] = Σ_{j in chunk z} (Σ_hd att_hd[i][j]) h[j][c] ----------------
// Computes OUT^T tiles: D[m=c][n=i] = Σ_j hT[c][j] * W[i][j]
// A = hT tile [128 c][64 j] bf16 (staged, XOR-swizzled)
// B = W  tile [128 i][64 j] bf16 (generated in fp32, cvt, XOR-swizzled)
template<int ACT, int NH>
__global__ __launch_bounds__(256)
void att_mfma(const u16* __restrict__ hT, const float* __restrict__ s1b,
              const float* __restrict__ s2b, const float* __restrict__ qb,
              const u64* __restrict__ bits, float* __restrict__ partial,
              int Ncols, int njt)
{
    __shared__ u16 Wl[128 * 64];
    __shared__ u16 Al[128 * 64];
    __shared__ float s1s[NH][128];
    __shared__ float qs[NH][128];
    const int t    = threadIdx.x;
    const int i0   = blockIdx.x * 128;
    const int c0   = blockIdx.y * 128;
    const int z    = blockIdx.z;
    const int jt0  = z * njt;
    const int lane = t & 63, wv = t >> 6;
    const int l15  = lane & 15, l4 = lane >> 4;

    for (int u = t; u < NH * 128; u += 256) {
        int hd = u >> 7, iL = u & 127;
        s1s[hd][iL] = s1b[hd * N_NODES + i0 + iL];
        qs[hd][iL]  = qb[hd * N_NODES + i0 + iL];
    }

    f32x4 acc[4][4] = {};                 // acc[r(m=c)][n(i)]
    const int mrow0 = 64 * (wv & 1);      // c-dim base within 128-tile
    const int nrow0 = 64 * (wv >> 1);     // i-dim base

    for (int jt = jt0; jt < jt0 + njt; ++jt) {
        const int j0 = jt << 6;
        __syncthreads();                  // protect LDS (also covers s1s preload on iter 0)
        // --- phase W: generate weights, rows iL = 4*rr + wv, col = lane ---
        float s2v[NH];
        #pragma unroll
        for (int hd = 0; hd < NH; ++hd) s2v[hd] = s2b[hd * N_NODES + j0 + lane];
        #pragma unroll 4
        for (int rr = 0; rr < 32; ++rr) {
            const int iL = (rr << 2) | wv;
            const u64 wd = bits[((size_t)(i0 + iL) << 6) + jt];
            float w = 0.f;
            if ((wd >> lane) & 1ull) {
                #pragma unroll
                for (int hd = 0; hd < NH; ++hd)
                    w += __expf(actf<ACT>(s1s[hd][iL] + s2v[hd]) - qs[hd][iL]);
            }
            Wl[iL * 64 + (lane ^ ((iL & 7) << 3))] = f2bf(w);
        }
        // --- phase A: stage hT[c0..+128][j0..+64] (reg-staged, swizzled write) ---
        {
            const int blk = t & 7;
            #pragma unroll
            for (int q = 0; q < 4; ++q) {
                const int row = (t >> 3) + (q << 5);
                const uint4 v = *(const uint4*)(hT + (size_t)(c0 + row) * N_NODES + j0 + (blk << 3));
                *(uint4*)&Al[row * 64 + (((blk << 3) ^ ((row & 7) << 3)))] = v;
            }
        }
        __syncthreads();
        // --- phase MFMA ---
        #pragma unroll
        for (int kk = 0; kk < 2; ++kk) {
            bf16x8 af[4], bfr[4];
            const int colu = (l4 << 3) + (kk << 5);
            #pragma unroll
            for (int r = 0; r < 4; ++r) {
                const int row = mrow0 + (r << 4) + l15;
                af[r] = *(const bf16x8*)&Al[row * 64 + (colu ^ ((row & 7) << 3))];
            }
            #pragma unroll
            for (int n = 0; n < 4; ++n) {
                const int row = nrow0 + (n << 4) + l15;
                bfr[n] = *(const bf16x8*)&Wl[row * 64 + (colu ^ ((row & 7) << 3))];
            }
            #pragma unroll
            for (int r = 0; r < 4; ++r)
                #pragma unroll
                for (int n = 0; n < 4; ++n)
                    acc[r][n] = __builtin_amdgcn_mfma_f32_16x16x32_bf16(af[r], bfr[n], acc[r][n], 0, 0, 0);
        }
    }
    // --- store partial[z]: D[m][n] -> m = c (4 consecutive per lane), n = i ---
    float* pz = partial + (size_t)z * N_NODES * Ncols;
    #pragma unroll
    for (int n = 0; n < 4; ++n) {
        const int i = i0 + nrow0 + (n << 4) + l15;
        #pragma unroll
        for (int r = 0; r < 4; ++r) {
            const int c = c0 + mrow0 + (r << 4) + (l4 << 2);
            *(f32x4*)&pz[(size_t)i * Ncols + c] = acc[r][n];
        }
    }
}

// ---------------- GAT reduce: xacc (+)= l2norm(elu(0.99*Σz part + 0.01h)) + b ----------------
template<int FIRST>
__global__ __launch_bounds__(128)
void reduce_gat(const float* __restrict__ part, const float* __restrict__ h,
                const float* __restrict__ bias, float* __restrict__ xacc)
{
    __shared__ float red[2];
    const int i = blockIdx.x, t = threadIdx.x;
    float g[3]; float ss = 0.f;
    #pragma unroll
    for (int u = 0; u < 3; ++u) {
        const int c = t + u * 128;
        float s = 0.f;
        #pragma unroll
        for (int zz = 0; zz < 8; ++zz) s += part[((size_t)zz * N_NODES + i) * H1 + c];
        float v = eluf(0.99f * s + 0.01f * h[(size_t)i * H1 + c]);
        g[u] = v; ss += v * v;
    }
    ss = waveReduceSum(ss);
    if ((t & 63) == 0) red[t >> 6] = ss;
    __syncthreads();
    float inv = 1.f / fmaxf(sqrtf(red[0] + red[1]), 1e-12f);
    float* xp = xacc + (size_t)i * H1;
    #pragma unroll
    for (int u = 0; u < 3; ++u) {
        int c = t + u * 128;
        float val = g[u] * inv + bias[c];
        if (FIRST) xp[c] = val; else xp[c] += val;
    }
}

// ---------------- conv(K=129, 3 ch) + elu + channel-combine -> hcore ----------------
__global__ __launch_bounds__(256)
void conv_combine(const float* __restrict__ xacc, const float* __restrict__ w_mid,
                  const float* __restrict__ b_mid, const float* __restrict__ w_core,
                  const float* __restrict__ b_core, float* __restrict__ hcore)
{
    __shared__ float row[H1];
    __shared__ float wm[3 * K_MID];
    const int n = blockIdx.x, t = threadIdx.x;
    for (int k = t; k < H1; k += 256) row[k] = eluf(xacc[(size_t)n * H1 + k] * (1.f / 3.f));
    for (int k = t; k < 3 * K_MID; k += 256) wm[k] = w_mid[k];
    __syncthreads();
    const int w = t;
    float a0 = 0.f, a1 = 0.f, a2 = 0.f;
    for (int k = 0; k < K_MID; ++k) {
        float xv = row[w + k];
        a0 += xv * wm[k];
        a1 += xv * wm[K_MID + k];
        a2 += xv * wm[2 * K_MID + k];
    }
    float hv = eluf(a0 + b_mid[0]) * w_core[0]
             + eluf(a1 + b_mid[1]) * w_core[1]
             + eluf(a2 + b_mid[2]) * w_core[2] + b_core[0];
    hcore[(size_t)n * H2 + w] = hv;
}

// ---------------- core reduce: embed = l2norm(elu(0.125*Σz part + 0.5*hcore)) + cbias ----------------
__global__ __launch_bounds__(256)
void reduce_core(const float* __restrict__ part, const float* __restrict__ hcore,
                 const float* __restrict__ cbias, float* __restrict__ embed)
{
    __shared__ float red[4];
    const int i = blockIdx.x, t = threadIdx.x;
    float s = 0.f;
    #pragma unroll
    for (int zz = 0; zz < 8; ++zz) s += part[((size_t)zz * N_NODES + i) * H2 + t];
    float v = eluf(0.125f * s + 0.5f * hcore[(size_t)i * H2 + t]);
    float ss = waveReduceSum(v * v);
    if ((t & 63) == 0) red[t >> 6] = ss;
    __syncthreads();
    float inv = 1.f / fmaxf(sqrtf(red[0] + red[1] + red[2] + red[3]), 1e-12f);
    embed[(size_t)i * H2 + t] = v * inv + cbias[t];
}

// ---------------- pred[e] = tf[src[e]] . tg[dst[e]] ----------------
__global__ __launch_bounds__(256)
void gather_dot(const float* __restrict__ tf, const float* __restrict__ tg,
                const int* __restrict__ ts, float* __restrict__ pred)
{
    const int e = blockIdx.x * 4 + (threadIdx.x >> 6);
    const int lane = threadIdx.x & 63;
    const int i0 = ts[(size_t)e * 2], i1 = ts[(size_t)e * 2 + 1];
    const float* a = tf + (size_t)i0 * D_OUT;
    const float* b = tg + (size_t)i1 * D_OUT;
    float p = a[lane] * b[lane] + a[lane + 64] * b[lane + 64];
    p = waveReduceSum(p);
    if (lane == 0) pred[e] = p;
}

// ---------------- launch ----------------
extern "C" void kernel_launch(void* const* d_in, const int* in_sizes, int n_in,
                              void* d_out, int out_size, void* d_ws, size_t ws_size,
                              hipStream_t stream)
{
    const float* x1     = (const float*)d_in[0];
    const float* x2     = (const float*)d_in[1];
    const float* x3     = (const float*)d_in[2];
    const int*   adj    = (const int*)d_in[3];
    const int*   ts     = (const int*)d_in[4];
    const float* gat_W  = (const float*)d_in[5];
    const float* gat_a  = (const float*)d_in[6];
    const float* gat_b  = (const float*)d_in[7];
    const float* w_mid  = (const float*)d_in[8];
    const float* b_mid  = (const float*)d_in[9];
    const float* w_core = (const float*)d_in[10];
    const float* b_core = (const float*)d_in[11];
    const float* a_core = (const float*)d_in[12];
    const float* cbias  = (const float*)d_in[13];
    const float* W_tf1  = (const float*)d_in[14];
    const float* b_tf1  = (const float*)d_in[15];
    const float* W_tf2  = (const float*)d_in[16];
    const float* b_tf2  = (const float*)d_in[17];
    const float* W_tg1  = (const float*)d_in[18];
    const float* b_tg1  = (const float*)d_in[19];
    const float* W_tg2  = (const float*)d_in[20];
    const float* b_tg2  = (const float*)d_in[21];

    // ---- workspace layout ----
    const int NWORDS = N_NODES * (N_NODES / 64);
    const size_t HSZ = (size_t)N_NODES * H1;            // 1.57M floats
    u64*   bits = (u64*)d_ws;
    float* fw   = (float*)d_ws;
    size_t off  = (size_t)NWORDS * 2;
    float* s1b  = fw + off;  off += 4 * (size_t)N_NODES;
    float* s2b  = fw + off;  off += 4 * (size_t)N_NODES;
    float* qb   = fw + off;  off += 4 * (size_t)N_NODES;
    float* h3   = fw + off;  off += 3 * HSZ;            // 3 GAT h (fp32)
    float* xacc = fw + off;  off += HSZ;
    u16*   hT   = (u16*)(fw + off); off += HSZ / 2;     // bf16 transposed h
    float* partial = fw + off;  off += 8 * HSZ;         // z-partials (48MB)
    // aliases
    float* hcore = h3;                                   // N*H2
    float* embed = h3 + HSZ;                             // N*H2
    float* t1f   = partial;                              // N*H3
    float* t1g   = partial + (size_t)N_NODES * H3;
    float* tf    = h3 + 2 * HSZ;                         // N*D_OUT
    float* tg    = tf + (size_t)N_NODES * D_OUT;
    float* pred  = (float*)d_out;

    const dim3 blk(256);

    // ---- adj -> bitmask ----
    pack_adj<<<dim3(1024), blk, 0, stream>>>(adj, bits, NWORDS);

    // ---- stage 1: batched x@W, logits ----
    {
        GP gp;
        gp.A[0] = x1; gp.A[1] = x2; gp.A[2] = x3;
        for (int c = 0; c < 3; ++c) {
            gp.B[c]    = gat_W + (size_t)c * D_IN * H1;
            gp.bias[c] = nullptr;
            gp.C[c]    = h3 + (size_t)c * HSZ;
        }
        gemm_f32<0><<<dim3(N_NODES / 64, H1 / 128, 3), blk, 0, stream>>>(gp, N_NODES, D_IN, H1);
    }
    rowdot2<<<dim3(N_NODES, 3), dim3(64), 0, stream>>>(h3, HSZ, gat_a, H1, s1b, s2b);
    softmax_stats<0><<<dim3(N_NODES, 3), blk, 0, stream>>>(s1b, s2b, bits, qb);

    // ---- per-channel: transpose, MFMA att, reduce ----
    for (int c = 0; c < 3; ++c) {
        const float* hc = h3 + (size_t)c * HSZ;
        transpose_cvt<<<dim3(64, 6), blk, 0, stream>>>(hc, hT, H1);
        att_mfma<0, 1><<<dim3(32, 3, 8), blk, 0, stream>>>(
            hT, s1b + (size_t)c * N_NODES, s2b + (size_t)c * N_NODES,
            qb + (size_t)c * N_NODES, bits, partial, H1, 8);
        if (c == 0)
            reduce_gat<1><<<dim3(N_NODES), dim3(128), 0, stream>>>(partial, hc, gat_b + (size_t)c * H1, xacc);
        else
            reduce_gat<0><<<dim3(N_NODES), dim3(128), 0, stream>>>(partial, hc, gat_b + (size_t)c * H1, xacc);
    }

    // ---- stage 2: conv + combine ----
    conv_combine<<<dim3(N_NODES), blk, 0, stream>>>(xacc, w_mid, b_mid, w_core, b_core, hcore);

    // ---- stage 3: collapsed 4-head core attention ----
    rowdot2<<<dim3(N_NODES, 4), dim3(64), 0, stream>>>(hcore, 0, a_core, H2, s1b, s2b);
    softmax_stats<1><<<dim3(N_NODES, 4), blk, 0, stream>>>(s1b, s2b, bits, qb);
    transpose_cvt<<<dim3(64, 4), blk, 0, stream>>>(hcore, hT, H2);
    att_mfma<1, 4><<<dim3(32, 2, 8), blk, 0, stream>>>(hT, s1b, s2b, qb, bits, partial, H2, 8);
    reduce_core<<<dim3(N_NODES), blk, 0, stream>>>(partial, hcore, cbias, embed);

    // ---- stage 4: final MLPs + edge dots ----
    {
        GP gp;
        gp.A[0] = embed; gp.A[1] = embed; gp.A[2] = embed;
        gp.B[0] = W_tf1; gp.B[1] = W_tg1; gp.B[2] = W_tg1;
        gp.bias[0] = b_tf1; gp.bias[1] = b_tg1; gp.bias[2] = b_tg1;
        gp.C[0] = t1f; gp.C[1] = t1g; gp.C[2] = t1g;
        gemm_f32<1><<<dim3(N_NODES / 64, H3 / 128, 2), blk, 0, stream>>>(gp, N_NODES, H2, H3);
    }
    {
        GP gp;
        gp.A[0] = t1f; gp.A[1] = t1g; gp.A[2] = t1g;
        gp.B[0] = W_tf2; gp.B[1] = W_tg2; gp.B[2] = W_tg2;
        gp.bias[0] = b_tf2; gp.bias[1] = b_tg2; gp.bias[2] = b_tg2;
        gp.C[0] = tf; gp.C[1] = tg; gp.C[2] = tg;
        gemm_f32<1><<<dim3(N_NODES / 64, D_OUT / 128, 2), blk, 0, stream>>>(gp, N_NODES, H3, D_OUT);
    }
    gather_dot<<<dim3(E_EDGES / 4), blk, 0, stream>>>(tf, tg, ts, pred);
}